// Round 3
// baseline (882.986 us; speedup 1.0000x reference)
//
#include <hip/hip_runtime.h>

// SSIM 3D loss: pred/target f32 [4,1,64,192,192], scalar 1 - mean(ssim_map).
// v3 = v2 with ramp-in guards fixed in both accumulator-trick phases.
//   A: fused W+H blur -> 5 fp16 field volumes (register-window W phase,
//      11-slot accumulator-trick H phase with ramp-in guard)
//   B: D blur via 11-slot accumulator trick (ramp-in peeled+guarded) + SSIM
//   C: finalize.

#define D_DIM 64
#define H_DIM 192
#define W_DIM 192
#define SLICE (H_DIM * W_DIM)   // 36864
#define VOL   (D_DIM * SLICE)   // 2359296
#define NB    4
#define KS    11
#define RAD   5
#define TH    32
#define TW    32
#define HT    (TH + 2 * RAD)    // 42 halo rows
#define WT    (TW + 2 * RAD)    // 42 halo cols
#define SPITCH 43               // staging pitch
#define IPITCH 33               // interm pitch
#define IPF   (HT * IPITCH)     // floats per interm field
#define C1F   (0.01f * 0.01f)
#define C2F   (0.03f * 0.03f)

__device__ __forceinline__ void make_window(float* g) {
    float s = 0.f;
#pragma unroll
    for (int i = 0; i < KS; ++i) {
        float c = (float)(i - RAD);
        g[i] = expf(-(c * c) * (1.0f / 4.5f));  // 2*sigma^2 = 4.5
        s += g[i];
    }
    float inv = 1.0f / s;
#pragma unroll
    for (int i = 0; i < KS; ++i) g[i] *= inv;
}

// ---- Kernel A: W+H blur of 5 derived fields for one (b,d) slice tile ----
__global__ __launch_bounds__(256) void hw_blur_kernel(
    const float* __restrict__ pred, const float* __restrict__ targ,
    _Float16* __restrict__ fields, int b0, int fvol) {
    __shared__ float sp[HT * SPITCH];
    __shared__ float st[HT * SPITCH];
    __shared__ float interm[5 * IPF];

    float g[KS];
    make_window(g);

    const int tid = threadIdx.x;
    const int d    = blockIdx.y;
    const int tile = blockIdx.x;              // 0..35
    const int h0 = (tile / 6) * TH;
    const int w0 = (tile % 6) * TW;
    const int bl = blockIdx.z;

    const int in_base = (b0 + bl) * VOL + d * SLICE;

    // ---- Stage p/t halo tiles (zero-padded at H/W edges and pad col) ----
    for (int i = tid; i < HT * SPITCH; i += 256) {
        int y = i / SPITCH, x = i - y * SPITCH;
        int gh = h0 + y - RAD, gw = w0 + x - RAD;
        float pv = 0.f, tv = 0.f;
        if (x < WT && (unsigned)gh < (unsigned)H_DIM && (unsigned)gw < (unsigned)W_DIM) {
            int idx = in_base + gh * W_DIM + gw;
            pv = pred[idx];
            tv = targ[idx];
        }
        sp[i] = pv;
        st[i] = tv;
    }
    __syncthreads();

    // ---- Phase W: register-window blur along W, derive 5 fields ----
    // 168 tasks: y in [0,42) halo rows x 4 segments of 8 outputs
    if (tid < 168) {
        const int y = tid >> 2;
        const int x0 = (tid & 3) * 8;
        float wp[18], wt[18];
#pragma unroll
        for (int k = 0; k < 18; ++k) {
            wp[k] = sp[y * SPITCH + x0 + k];
            wt[k] = st[y * SPITCH + x0 + k];
        }
#pragma unroll
        for (int o = 0; o < 8; ++o) {
            float s0 = 0.f, s1 = 0.f, s2 = 0.f, s3 = 0.f, s4 = 0.f;
#pragma unroll
            for (int k = 0; k < KS; ++k) {
                float pv = wp[o + k], tv = wt[o + k], gk = g[k];
                s0 += gk * pv;
                s1 += gk * tv;
                s2 += gk * pv * pv;
                s3 += gk * tv * tv;
                s4 += gk * pv * tv;
            }
            int idx = y * IPITCH + x0 + o;
            interm[0 * IPF + idx] = s0;
            interm[1 * IPF + idx] = s1;
            interm[2 * IPF + idx] = s2;
            interm[3 * IPF + idx] = s3;
            interm[4 * IPF + idx] = s4;
        }
    }
    __syncthreads();

    // ---- Phase H: accumulator-trick blur along H, emit fp16 fields ----
    // out[y] = sum_k g[k] * in_halo[y+k].  Row yy feeds outputs y = yy-10..yy
    // (slot (yy+m+1)%11 gets weight g[10-m], i.e. output y = yy-10+m).
    // Ramp-in guard: skip m < 10-yy (outputs y < 0) for yy < 10.
    if (tid < 160) {
        const int f = tid >> 5;
        const int x = tid & 31;
        const float* col = interm + f * IPF + x;
        _Float16* outf = fields + (size_t)f * fvol + bl * VOL + d * SLICE
                       + h0 * W_DIM + w0 + x;
        float acc[KS];
#pragma unroll
        for (int s = 0; s < KS; ++s) acc[s] = 0.f;
#pragma unroll
        for (int yy = 0; yy < HT; ++yy) {
            float v = col[yy * IPITCH];
#pragma unroll
            for (int m = 0; m < KS; ++m) {
                if (yy < 10 && m < 10 - yy) continue;   // ramp-in guard (folds)
                acc[(yy + m + 1) % KS] += g[10 - m] * v;
            }
            if (yy >= 10) {
                const int y = yy - 10;
                const int s = (yy + 1) % KS;
                outf[y * W_DIM] = (_Float16)acc[s];
                acc[s] = 0.f;
            }
        }
    }
}

__device__ __forceinline__ float ssim_from_acc(const float acc[5][KS], int es) {
    float mu_p = acc[0][es], mu_t = acc[1][es];
    float ep2 = acc[2][es], et2 = acc[3][es], ept = acc[4][es];
    float mu_p_sq = mu_p * mu_p, mu_t_sq = mu_t * mu_t;
    float mu_pt = mu_p * mu_t;
    float num = (2.f * mu_pt + C1F) * (2.f * (ept - mu_pt) + C2F);
    float den = (mu_p_sq + mu_t_sq + C1F) *
                ((ep2 - mu_p_sq) + (et2 - mu_t_sq) + C2F);
    return num / den;
}

// ---- Kernel B: D blur via 11-slot accumulator trick + SSIM + partials ----
// Plane dd feeds outputs d = dd-5..dd+5 (j = d-dd+5, slot (dd+j+6)%11,
// weight g[j]). After plane dd, output d = dd-5 is complete in slot (dd+6)%11.
// Ramp-in guard: for dd < 5, skip j < 5-dd (outputs d < 0).
__global__ __launch_bounds__(256) void dblur_ssim_kernel(
    const _Float16* __restrict__ fields, float* __restrict__ partials,
    int fvol) {
    float g[KS];
    make_window(g);

    const int tid = threadIdx.x;
    const int bl = blockIdx.x / 144;                 // local batch
    const int hw = (blockIdx.x % 144) * 256 + tid;   // 0..SLICE-1
    const int cb = bl * VOL + hw;

    float acc[5][KS];
#pragma unroll
    for (int f = 0; f < 5; ++f)
#pragma unroll
        for (int s = 0; s < KS; ++s) acc[f][s] = 0.f;

    float ssim_sum = 0.f;

    // ---- ramp-in: planes 0..10, compile-time dd, guarded ----
#pragma unroll
    for (int dd = 0; dd < KS; ++dd) {
        float v[5];
        const int off = cb + dd * SLICE;
#pragma unroll
        for (int f = 0; f < 5; ++f)
            v[f] = (float)fields[(size_t)f * fvol + off];
#pragma unroll
        for (int j = 0; j < KS; ++j) {
            if (dd < 5 && j < 5 - dd) continue;      // ramp-in guard (folds)
            const int s = (dd + j + 6) % KS;
            const float gj = g[j];
#pragma unroll
            for (int f = 0; f < 5; ++f) acc[f][s] += gj * v[f];
        }
        if (dd >= 5) {
            const int es = (dd + 6) % KS;
            ssim_sum += ssim_from_acc(acc, es);       // outputs 0..5
#pragma unroll
            for (int f = 0; f < 5; ++f) acc[f][es] = 0.f;
        }
    }

    // ---- steady state: planes 11..63 ----
#pragma unroll 1
    for (int blk = 1; blk < 6; ++blk) {
#pragma unroll
        for (int r = 0; r < KS; ++r) {
            const int dd = blk * KS + r;
            if (dd >= D_DIM) break;                   // blk=5: r < 9
            float v[5];
            const int off = cb + dd * SLICE;
#pragma unroll
            for (int f = 0; f < 5; ++f)
                v[f] = (float)fields[(size_t)f * fvol + off];
#pragma unroll
            for (int j = 0; j < KS; ++j) {
                const int s = (r + j + 6) % KS;
                const float gj = g[j];
#pragma unroll
                for (int f = 0; f < 5; ++f) acc[f][s] += gj * v[f];
            }
            const int es = (r + 6) % KS;              // output d = dd-5
            ssim_sum += ssim_from_acc(acc, es);
#pragma unroll
            for (int f = 0; f < 5; ++f) acc[f][es] = 0.f;
        }
    }

    // ---- ramp-out: outputs d = 59..63 from slots d%11 ----
#pragma unroll
    for (int d = 59; d < 64; ++d)
        ssim_sum += ssim_from_acc(acc, d % KS);

    // block reduction
    float a = ssim_sum;
#pragma unroll
    for (int off = 32; off > 0; off >>= 1) a += __shfl_down(a, off, 64);
    __shared__ float red[4];
    int lane = tid & 63, wv = tid >> 6;
    if (lane == 0) red[wv] = a;
    __syncthreads();
    if (tid == 0) partials[blockIdx.x] = red[0] + red[1] + red[2] + red[3];
}

// ---- Kernel C: final reduction ----
__global__ __launch_bounds__(256) void finalize_kernel(
    const float* __restrict__ partials, int n, float* __restrict__ out) {
    double a = 0.0;
    for (int i = threadIdx.x; i < n; i += 256) a += (double)partials[i];
#pragma unroll
    for (int off = 32; off > 0; off >>= 1) a += __shfl_down(a, off, 64);
    __shared__ double red[4];
    int lane = threadIdx.x & 63, wv = threadIdx.x >> 6;
    if (lane == 0) red[wv] = a;
    __syncthreads();
    if (threadIdx.x == 0) {
        double s = red[0] + red[1] + red[2] + red[3];
        out[0] = (float)(1.0 - s / (double)((long long)NB * VOL));
    }
}

extern "C" void kernel_launch(void* const* d_in, const int* in_sizes, int n_in,
                              void* d_out, int out_size, void* d_ws, size_t ws_size,
                              hipStream_t stream) {
    const float* pred = (const float*)d_in[0];
    const float* targ = (const float*)d_in[1];
    float* out = (float*)d_out;

    // batches per chunk G in {4,2,1} such that 5*G*VOL fp16 + partials fit
    int G = 4;
    while (G > 1 && (size_t)5 * G * VOL * 2 + 4096 > ws_size) G >>= 1;

    const int fvol = G * VOL;
    _Float16* fields = (_Float16*)d_ws;
    float* partials = (float*)((char*)d_ws + (size_t)5 * fvol * 2);
    const int blocks_per_chunk = G * 144;
    const int nchunks = NB / G;

    for (int c = 0; c < nchunks; ++c) {
        hw_blur_kernel<<<dim3(36, D_DIM, G), 256, 0, stream>>>(
            pred, targ, fields, c * G, fvol);
        dblur_ssim_kernel<<<dim3(blocks_per_chunk), 256, 0, stream>>>(
            fields, partials + c * blocks_per_chunk, fvol);
    }
    finalize_kernel<<<1, 256, 0, stream>>>(partials, NB * 144, out);
}

// Round 4
// 239.361 us; speedup vs baseline: 3.6889x; 3.6889x over previous
//
#include <hip/hip_runtime.h>

// SSIM 3D loss: pred/target f32 [4,1,64,192,192], scalar 1 - mean(ssim_map).
// v4: A = fused W+H blur -> 5 fp16 field volumes (register-window W phase,
//        accumulator-trick H phase, LDS-buffered coalesced fp16 store).
//     B = D blur via modular sliding window (slot = plane%11, all indices
//        literal via macro expansion; no shifts, no scratch), D split in two
//        halves per column for occupancy. SSIM + partial sums fused.
//     C = finalize.

#define D_DIM 64
#define H_DIM 192
#define W_DIM 192
#define SLICE (H_DIM * W_DIM)   // 36864
#define VOL   (D_DIM * SLICE)   // 2359296
#define NB    4
#define KS    11
#define RAD   5
#define TH    32
#define TW    32
#define HT    (TH + 2 * RAD)    // 42 halo rows
#define WT    (TW + 2 * RAD)    // 42 halo cols
#define SPITCH 43               // staging pitch
#define IPITCH 33               // interm pitch
#define IPF   (HT * IPITCH)
#define C1F   (0.01f * 0.01f)
#define C2F   (0.03f * 0.03f)

__device__ __forceinline__ void make_window(float* g) {
    float s = 0.f;
#pragma unroll
    for (int i = 0; i < KS; ++i) {
        float c = (float)(i - RAD);
        g[i] = expf(-(c * c) * (1.0f / 4.5f));  // 2*sigma^2 = 4.5
        s += g[i];
    }
    float inv = 1.0f / s;
#pragma unroll
    for (int i = 0; i < KS; ++i) g[i] *= inv;
}

// ---- Kernel A: W+H blur of 5 derived fields for one (b,d) slice tile ----
__global__ __launch_bounds__(256) void hw_blur_kernel(
    const float* __restrict__ pred, const float* __restrict__ targ,
    _Float16* __restrict__ fields, int b0, int fvol) {
    __shared__ union U {
        float stage[2 * HT * SPITCH];      // sp | st
        _Float16 obuf[5 * TH * TW];        // reused after W phase
    } u;
    __shared__ float interm[5 * IPF];
    float* sp = u.stage;
    float* st = u.stage + HT * SPITCH;

    float g[KS];
    make_window(g);

    const int tid = threadIdx.x;
    const int d    = blockIdx.y;
    const int tile = blockIdx.x;              // 0..35
    const int h0 = (tile / 6) * TH;
    const int w0 = (tile % 6) * TW;
    const int bl = blockIdx.z;

    const int in_base = (b0 + bl) * VOL + d * SLICE;

    // ---- Stage p/t halo tiles (zero-padded at H/W edges and pad col) ----
    for (int i = tid; i < HT * SPITCH; i += 256) {
        int y = i / SPITCH, x = i - y * SPITCH;
        int gh = h0 + y - RAD, gw = w0 + x - RAD;
        float pv = 0.f, tv = 0.f;
        if (x < WT && (unsigned)gh < (unsigned)H_DIM && (unsigned)gw < (unsigned)W_DIM) {
            int idx = in_base + gh * W_DIM + gw;
            pv = pred[idx];
            tv = targ[idx];
        }
        sp[i] = pv;
        st[i] = tv;
    }
    __syncthreads();

    // ---- Phase W: register-window blur along W, derive 5 fields ----
    if (tid < 168) {
        const int y = tid >> 2;
        const int x0 = (tid & 3) * 8;
        float wp[18], wt[18];
#pragma unroll
        for (int k = 0; k < 18; ++k) {
            wp[k] = sp[y * SPITCH + x0 + k];
            wt[k] = st[y * SPITCH + x0 + k];
        }
#pragma unroll
        for (int o = 0; o < 8; ++o) {
            float s0 = 0.f, s1 = 0.f, s2 = 0.f, s3 = 0.f, s4 = 0.f;
#pragma unroll
            for (int k = 0; k < KS; ++k) {
                float pv = wp[o + k], tv = wt[o + k], gk = g[k];
                s0 += gk * pv;
                s1 += gk * tv;
                s2 += gk * pv * pv;
                s3 += gk * tv * tv;
                s4 += gk * pv * tv;
            }
            int idx = y * IPITCH + x0 + o;
            interm[0 * IPF + idx] = s0;
            interm[1 * IPF + idx] = s1;
            interm[2 * IPF + idx] = s2;
            interm[3 * IPF + idx] = s3;
            interm[4 * IPF + idx] = s4;
        }
    }
    __syncthreads();

    // ---- Phase H: accumulator-trick blur along H -> fp16 into LDS obuf ----
    // Row yy feeds outputs y = yy-10..yy: slot (yy+m+1)%11 gets g[10-m].
    // Ramp-in guard: skip m < 10-yy for yy < 10 (outputs y < 0).
    if (tid < 160) {
        const int f = tid >> 5;
        const int x = tid & 31;
        const float* col = interm + f * IPF + x;
        _Float16* ob = u.obuf + (f * TH) * TW + x;
        float acc[KS];
#pragma unroll
        for (int s = 0; s < KS; ++s) acc[s] = 0.f;
#pragma unroll
        for (int yy = 0; yy < HT; ++yy) {
            float v = col[yy * IPITCH];
#pragma unroll
            for (int m = 0; m < KS; ++m) {
                if (yy < 10 && m < 10 - yy) continue;   // folds at compile time
                acc[(yy + m + 1) % KS] += g[10 - m] * v;
            }
            if (yy >= 10) {
                const int y = yy - 10;
                const int s = (yy + 1) % KS;
                ob[y * TW] = (_Float16)acc[s];
                acc[s] = 0.f;
            }
        }
    }
    __syncthreads();

    // ---- Store phase: coalesced 4B stores of the 5x32x32 fp16 tile ----
    const unsigned* ob32 = (const unsigned*)u.obuf;
    const int out_base = bl * VOL + d * SLICE;
#pragma unroll
    for (int it = 0; it < 10; ++it) {              // 2560 uints / 256 threads
        int i = it * 256 + tid;
        int h2 = i * 2;                            // index in halves
        int f = h2 >> 10;                          // / (32*32)
        int rem = h2 & 1023;
        int y = rem >> 5, x = rem & 31;
        unsigned val = ob32[i];
        *(unsigned*)(fields + (size_t)f * fvol + out_base +
                     (h0 + y) * W_DIM + w0 + x) = val;
    }
}

// ================= Kernel B: D blur + SSIM + partial sums =================
// Modular sliding window: slot s holds plane p with p%11 == s among the last
// 11 planes loaded. All slot indices are literals via macro expansion.

#define LOADP(s, q) do {                                                  \
    const int _o = (q) * SLICE;                                           \
    w0[s] = (float)f0[_o]; w1[s] = (float)f1[_o]; w2[s] = (float)f2[_o];  \
    w3[s] = (float)f3[_o]; w4[s] = (float)f4[_o];                         \
} while (0)

#define SSIM_ACC(MP, MT, E2, T2, PT) do {                                 \
    float _mps = (MP) * (MP), _mts = (MT) * (MT), _mpt = (MP) * (MT);     \
    float _num = (2.f * _mpt + C1F) * (2.f * ((PT) - _mpt) + C2F);        \
    float _den = (_mps + _mts + C1F) *                                    \
                 (((E2) - _mps) + ((T2) - _mts) + C2F);                   \
    ssim_sum += _num * __builtin_amdgcn_rcpf(_den);                       \
} while (0)

// emit output d with r = (d-6) mod 11: window slots (1+r+j)%11, j=0..JHI
#define EMIT_W(r, JHI) do {                                               \
    float _mp = 0.f, _mt = 0.f, _e2 = 0.f, _t2 = 0.f, _pt = 0.f;          \
    _Pragma("unroll")                                                     \
    for (int _j = 0; _j <= (JHI); ++_j) {                                 \
        const int _s = (1 + (r) + _j) % 11; const float _g = g[_j];       \
        _mp += _g * w0[_s]; _mt += _g * w1[_s]; _e2 += _g * w2[_s];       \
        _t2 += _g * w3[_s]; _pt += _g * w4[_s];                           \
    }                                                                     \
    SSIM_ACC(_mp, _mt, _e2, _t2, _pt);                                    \
} while (0)

// ramp-in emit for output d in [0,5]: planes 0..d+5 at slot = plane
#define EMIT_IN(d) do {                                                   \
    float _mp = 0.f, _mt = 0.f, _e2 = 0.f, _t2 = 0.f, _pt = 0.f;          \
    _Pragma("unroll")                                                     \
    for (int _j = 5 - (d); _j < 11; ++_j) {                               \
        const int _s = (d) - 5 + _j; const float _g = g[_j];              \
        _mp += _g * w0[_s]; _mt += _g * w1[_s]; _e2 += _g * w2[_s];       \
        _t2 += _g * w3[_s]; _pt += _g * w4[_s];                           \
    }                                                                     \
    SSIM_ACC(_mp, _mt, _e2, _t2, _pt);                                    \
} while (0)

#define STEP(r, q) do { LOADP(r, q); EMIT_W(r, 10); } while (0)

__global__ __launch_bounds__(256) void dblur_ssim_kernel(
    const _Float16* __restrict__ fields, float* __restrict__ partials,
    int fvol) {
    float g[KS];
    make_window(g);

    const int tid = threadIdx.x;
    const int bl = blockIdx.x / 144;                 // local batch
    const int hw = (blockIdx.x % 144) * 256 + tid;   // 0..SLICE-1
    const int cb = bl * VOL + hw;
    const size_t fv = (size_t)fvol;
    const _Float16* f0 = fields + cb;
    const _Float16* f1 = fields + fv + cb;
    const _Float16* f2 = fields + 2 * fv + cb;
    const _Float16* f3 = fields + 3 * fv + cb;
    const _Float16* f4 = fields + 4 * fv + cb;

    float w0[KS], w1[KS], w2[KS], w3[KS], w4[KS];
    float ssim_sum = 0.f;

    if (blockIdx.y == 0) {
        // ---- outputs d = 0..31, planes 0..36 ----
        LOADP(0, 0); LOADP(1, 1); LOADP(2, 2); LOADP(3, 3); LOADP(4, 4);
        LOADP(5, 5); LOADP(6, 6); LOADP(7, 7); LOADP(8, 8); LOADP(9, 9);
        LOADP(10, 10);
        EMIT_IN(0); EMIT_IN(1); EMIT_IN(2); EMIT_IN(3); EMIT_IN(4); EMIT_IN(5);
#pragma unroll 1
        for (int b = 0; b < 2; ++b) {                 // d = 6..27
            const int qb = 11 + 11 * b;
            STEP(0, qb + 0); STEP(1, qb + 1); STEP(2, qb + 2); STEP(3, qb + 3);
            STEP(4, qb + 4); STEP(5, qb + 5); STEP(6, qb + 6); STEP(7, qb + 7);
            STEP(8, qb + 8); STEP(9, qb + 9); STEP(10, qb + 10);
        }
        // d = 28..31: planes 33..36
        STEP(0, 33); STEP(1, 34); STEP(2, 35); STEP(3, 36);
    } else {
        // ---- outputs d = 32..63, planes 27..63 ----
        // preload planes 27..37 at slot plane%11 = (5+i)%11
        LOADP(5, 27); LOADP(6, 28); LOADP(7, 29); LOADP(8, 30); LOADP(9, 31);
        LOADP(10, 32); LOADP(0, 33); LOADP(1, 34); LOADP(2, 35); LOADP(3, 36);
        LOADP(4, 37);
        EMIT_W(4, 10);                                // d = 32 (planes 27..37)
        // d = 33..38: planes 38..43
        STEP(5, 38); STEP(6, 39); STEP(7, 40); STEP(8, 41); STEP(9, 42);
        STEP(10, 43);
        {                                             // d = 39..49: planes 44..54
            const int qb = 44;
            STEP(0, qb + 0); STEP(1, qb + 1); STEP(2, qb + 2); STEP(3, qb + 3);
            STEP(4, qb + 4); STEP(5, qb + 5); STEP(6, qb + 6); STEP(7, qb + 7);
            STEP(8, qb + 8); STEP(9, qb + 9); STEP(10, qb + 10);
        }
        // d = 50..58: planes 55..63
        STEP(0, 55); STEP(1, 56); STEP(2, 57); STEP(3, 58); STEP(4, 59);
        STEP(5, 60); STEP(6, 61); STEP(7, 62); STEP(8, 63);
        // ramp-out d = 59..63 (truncated windows, no loads)
        EMIT_W(9, 9); EMIT_W(10, 8); EMIT_W(11, 7); EMIT_W(12, 6); EMIT_W(13, 5);
    }

    // block reduction
    float a = ssim_sum;
#pragma unroll
    for (int off = 32; off > 0; off >>= 1) a += __shfl_down(a, off, 64);
    __shared__ float red[4];
    int lane = tid & 63, wv = tid >> 6;
    if (lane == 0) red[wv] = a;
    __syncthreads();
    if (tid == 0)
        partials[blockIdx.y * gridDim.x + blockIdx.x] =
            red[0] + red[1] + red[2] + red[3];
}

// ---- Kernel C: final reduction ----
__global__ __launch_bounds__(256) void finalize_kernel(
    const float* __restrict__ partials, int n, float* __restrict__ out) {
    double a = 0.0;
    for (int i = threadIdx.x; i < n; i += 256) a += (double)partials[i];
#pragma unroll
    for (int off = 32; off > 0; off >>= 1) a += __shfl_down(a, off, 64);
    __shared__ double red[4];
    int lane = threadIdx.x & 63, wv = threadIdx.x >> 6;
    if (lane == 0) red[wv] = a;
    __syncthreads();
    if (threadIdx.x == 0) {
        double s = red[0] + red[1] + red[2] + red[3];
        out[0] = (float)(1.0 - s / (double)((long long)NB * VOL));
    }
}

extern "C" void kernel_launch(void* const* d_in, const int* in_sizes, int n_in,
                              void* d_out, int out_size, void* d_ws, size_t ws_size,
                              hipStream_t stream) {
    const float* pred = (const float*)d_in[0];
    const float* targ = (const float*)d_in[1];
    float* out = (float*)d_out;

    // batches per chunk G in {4,2,1} such that fp16 fields + partials fit
    int G = 4;
    while (G > 1 && (size_t)5 * G * VOL * 2 + 8192 > ws_size) G >>= 1;

    const int fvol = G * VOL;
    _Float16* fields = (_Float16*)d_ws;
    float* partials = (float*)((char*)d_ws + (size_t)5 * fvol * 2);
    const int bpc = G * 144;                   // dblur blocks per (chunk, half)
    const int nchunks = NB / G;

    for (int c = 0; c < nchunks; ++c) {
        hw_blur_kernel<<<dim3(36, D_DIM, G), 256, 0, stream>>>(
            pred, targ, fields, c * G, fvol);
        dblur_ssim_kernel<<<dim3(bpc, 2), 256, 0, stream>>>(
            fields, partials + c * 2 * bpc, fvol);
    }
    finalize_kernel<<<1, 256, 0, stream>>>(partials, NB * 288, out);
}

// Round 6
// 216.476 us; speedup vs baseline: 4.0789x; 1.1057x over previous
//
#include <hip/hip_runtime.h>

// SSIM 3D loss: pred/target f32 [4,1,64,192,192], scalar 1 - mean(ssim_map).
// v5b: = v5 with the launch-site cast fixed (uint2* -> const h4*).
//     A = fused W+H blur, 32x48 tile (252/240 active lanes), fp16 interm
//        (40KB LDS -> 4 blocks/CU), outputs packed as X=[4 fields x fp16]
//        per pixel (8B) + Y=pt (2B) for vectorized downstream loads.
//     B = D blur, modular sliding window (literal slots via macros),
//        per-plane loads = 1 dwordx2 + 1 ushort. SSIM + partial sums.
//     C = finalize.

#define D_DIM 64
#define H_DIM 192
#define W_DIM 192
#define SLICE (H_DIM * W_DIM)   // 36864
#define VOL   (D_DIM * SLICE)   // 2359296
#define NB    4
#define KS    11
#define RAD   5
#define TH    32
#define TW    48
#define HT    (TH + 2 * RAD)    // 42 halo rows
#define WTT   (TW + 2 * RAD)    // 58 halo cols
#define SPITCH 59               // staging pitch (fp32)
#define IP2   48                // interm pitch (fp16 halves)
#define IPF2  (HT * IP2)        // 2016 halves per field
#define C1F   (0.01f * 0.01f)
#define C2F   (0.03f * 0.03f)

typedef _Float16 h4 __attribute__((ext_vector_type(4)));

__device__ __forceinline__ void make_window(float* g) {
    float s = 0.f;
#pragma unroll
    for (int i = 0; i < KS; ++i) {
        float c = (float)(i - RAD);
        g[i] = expf(-(c * c) * (1.0f / 4.5f));  // 2*sigma^2 = 4.5
        s += g[i];
    }
    float inv = 1.0f / s;
#pragma unroll
    for (int i = 0; i < KS; ++i) g[i] *= inv;
}

// ---- Kernel A: W+H blur of 5 derived fields for one (b,d) slice tile ----
__global__ __launch_bounds__(256) void hw_blur_kernel(
    const float* __restrict__ pred, const float* __restrict__ targ,
    uint2* __restrict__ Xg, unsigned short* __restrict__ Yg, int b0) {
    __shared__ union U {
        float stage[2 * HT * SPITCH];            // 19824 B: sp | st
        unsigned short obuf[5 * TH * TW];        // 15360 B, reused after W phase
    } u;
    __shared__ _Float16 interm2[5 * IPF2];       // 20160 B
    float* sp = u.stage;
    float* st = u.stage + HT * SPITCH;

    float g[KS];
    make_window(g);

    const int tid = threadIdx.x;
    const int d    = blockIdx.y;
    const int tile = blockIdx.x;              // 0..23
    const int h0 = (tile >> 2) * TH;          // 6 tiles in H
    const int w0 = (tile & 3) * TW;           // 4 tiles in W
    const int bl = blockIdx.z;

    const int in_base = (b0 + bl) * VOL + d * SLICE;

    // ---- Stage p/t halo tiles (zero-padded at H/W edges and pad col) ----
    for (int i = tid; i < HT * SPITCH; i += 256) {
        int y = i / SPITCH, x = i - y * SPITCH;
        int gh = h0 + y - RAD, gw = w0 + x - RAD;
        float pv = 0.f, tv = 0.f;
        if (x < WTT && (unsigned)gh < (unsigned)H_DIM && (unsigned)gw < (unsigned)W_DIM) {
            int idx = in_base + gh * W_DIM + gw;
            pv = pred[idx];
            tv = targ[idx];
        }
        sp[i] = pv;
        st[i] = tv;
    }
    __syncthreads();

    // ---- Phase W: register-window blur along W, derive 5 fields ----
    // 252 tasks: y in [0,42) halo rows x 6 segments of 8 outputs
    if (tid < 252) {
        const int y = tid / 6;
        const int x0 = (tid % 6) * 8;
        float wp[18], wt[18];
#pragma unroll
        for (int k = 0; k < 18; ++k) {
            wp[k] = sp[y * SPITCH + x0 + k];
            wt[k] = st[y * SPITCH + x0 + k];
        }
#pragma unroll
        for (int o = 0; o < 8; ++o) {
            float s0 = 0.f, s1 = 0.f, s2 = 0.f, s3 = 0.f, s4 = 0.f;
#pragma unroll
            for (int k = 0; k < KS; ++k) {
                float pv = wp[o + k], tv = wt[o + k], gk = g[k];
                s0 += gk * pv;
                s1 += gk * tv;
                s2 += gk * pv * pv;
                s3 += gk * tv * tv;
                s4 += gk * pv * tv;
            }
            int idx = y * IP2 + x0 + o;
            interm2[0 * IPF2 + idx] = (_Float16)s0;
            interm2[1 * IPF2 + idx] = (_Float16)s1;
            interm2[2 * IPF2 + idx] = (_Float16)s2;
            interm2[3 * IPF2 + idx] = (_Float16)s3;
            interm2[4 * IPF2 + idx] = (_Float16)s4;
        }
    }
    __syncthreads();

    // ---- Phase H: accumulator-trick blur along H -> fp16 into LDS obuf ----
    // Row yy feeds outputs y = yy-10..yy: slot (yy+m+1)%11 gets g[10-m].
    // Ramp-in guard: skip m < 10-yy for yy < 10 (outputs y < 0).
    // 240 tasks: field f in [0,5) x column x in [0,48)
    if (tid < 240) {
        const int f = tid / TW;
        const int x = tid % TW;
        const _Float16* col = interm2 + f * IPF2 + x;
        unsigned short* ob = u.obuf + f * (TH * TW) + x;
        float acc[KS];
#pragma unroll
        for (int s = 0; s < KS; ++s) acc[s] = 0.f;
#pragma unroll
        for (int yy = 0; yy < HT; ++yy) {
            float v = (float)col[yy * IP2];
#pragma unroll
            for (int m = 0; m < KS; ++m) {
                if (yy < 10 && m < 10 - yy) continue;   // folds at compile time
                acc[(yy + m + 1) % KS] += g[10 - m] * v;
            }
            if (yy >= 10) {
                const int y = yy - 10;
                const int s = (yy + 1) % KS;
                _Float16 h = (_Float16)acc[s];
                ob[y * TW] = *(unsigned short*)&h;
                acc[s] = 0.f;
            }
        }
    }
    __syncthreads();

    // ---- Store phase: gather 4 fields/px -> 8B X stores; pt -> 2B Y ----
    const size_t pl_base = (size_t)(bl * D_DIM + d) * SLICE;
#pragma unroll
    for (int it = 0; it < 6; ++it) {              // 1536 px / 256 threads
        int px = it * 256 + tid;
        int y = px / TW, x = px - y * TW;
        unsigned a0 = u.obuf[0 * (TH * TW) + px];
        unsigned a1 = u.obuf[1 * (TH * TW) + px];
        unsigned a2 = u.obuf[2 * (TH * TW) + px];
        unsigned a3 = u.obuf[3 * (TH * TW) + px];
        unsigned a4 = u.obuf[4 * (TH * TW) + px];
        size_t gi = pl_base + (size_t)(h0 + y) * W_DIM + (w0 + x);
        Xg[gi] = make_uint2(a0 | (a1 << 16), a2 | (a3 << 16));
        Yg[gi] = (unsigned short)a4;
    }
}

// ================= Kernel B: D blur + SSIM + partial sums =================
// Modular sliding window: slot s holds plane p with p%11 == s among the last
// 11 planes loaded. All slot indices are literals via macro expansion.

#define LOADP(s, q) do {                                                  \
    const int _o = (q) * SLICE;                                           \
    h4 _v = x4[_o];                                                       \
    w0[s] = (float)_v[0]; w1[s] = (float)_v[1];                           \
    w2[s] = (float)_v[2]; w3[s] = (float)_v[3];                           \
    w4[s] = (float)y1[_o];                                                \
} while (0)

#define SSIM_ACC(MP, MT, E2, T2, PT) do {                                 \
    float _mps = (MP) * (MP), _mts = (MT) * (MT), _mpt = (MP) * (MT);     \
    float _num = (2.f * _mpt + C1F) * (2.f * ((PT) - _mpt) + C2F);        \
    float _den = (_mps + _mts + C1F) *                                    \
                 (((E2) - _mps) + ((T2) - _mts) + C2F);                   \
    ssim_sum += _num * __builtin_amdgcn_rcpf(_den);                       \
} while (0)

// emit output d with r = (d-6) mod 11: window slots (1+r+j)%11, j=0..JHI
#define EMIT_W(r, JHI) do {                                               \
    float _mp = 0.f, _mt = 0.f, _e2 = 0.f, _t2 = 0.f, _pt = 0.f;          \
    _Pragma("unroll")                                                     \
    for (int _j = 0; _j <= (JHI); ++_j) {                                 \
        const int _s = (1 + (r) + _j) % 11; const float _g = g[_j];       \
        _mp += _g * w0[_s]; _mt += _g * w1[_s]; _e2 += _g * w2[_s];       \
        _t2 += _g * w3[_s]; _pt += _g * w4[_s];                           \
    }                                                                     \
    SSIM_ACC(_mp, _mt, _e2, _t2, _pt);                                    \
} while (0)

// ramp-in emit for output d in [0,5]: planes 0..d+5 at slot = plane
#define EMIT_IN(d) do {                                                   \
    float _mp = 0.f, _mt = 0.f, _e2 = 0.f, _t2 = 0.f, _pt = 0.f;          \
    _Pragma("unroll")                                                     \
    for (int _j = 5 - (d); _j < 11; ++_j) {                               \
        const int _s = (d) - 5 + _j; const float _g = g[_j];              \
        _mp += _g * w0[_s]; _mt += _g * w1[_s]; _e2 += _g * w2[_s];       \
        _t2 += _g * w3[_s]; _pt += _g * w4[_s];                           \
    }                                                                     \
    SSIM_ACC(_mp, _mt, _e2, _t2, _pt);                                    \
} while (0)

#define STEP(r, q) do { LOADP(r, q); EMIT_W(r, 10); } while (0)

__global__ __launch_bounds__(256) void dblur_ssim_kernel(
    const h4* __restrict__ Xg, const _Float16* __restrict__ Yg,
    float* __restrict__ partials) {
    float g[KS];
    make_window(g);

    const int tid = threadIdx.x;
    const int bl = blockIdx.x / 144;                 // local batch
    const int hw = (blockIdx.x % 144) * 256 + tid;   // 0..SLICE-1
    const int cb = bl * VOL + hw;
    const h4* x4 = Xg + cb;
    const _Float16* y1 = Yg + cb;

    float w0[KS], w1[KS], w2[KS], w3[KS], w4[KS];
    float ssim_sum = 0.f;

    if (blockIdx.y == 0) {
        // ---- outputs d = 0..31, planes 0..36 ----
        LOADP(0, 0); LOADP(1, 1); LOADP(2, 2); LOADP(3, 3); LOADP(4, 4);
        LOADP(5, 5); LOADP(6, 6); LOADP(7, 7); LOADP(8, 8); LOADP(9, 9);
        LOADP(10, 10);
        EMIT_IN(0); EMIT_IN(1); EMIT_IN(2); EMIT_IN(3); EMIT_IN(4); EMIT_IN(5);
#pragma unroll 1
        for (int b = 0; b < 2; ++b) {                 // d = 6..27
            const int qb = 11 + 11 * b;
            STEP(0, qb + 0); STEP(1, qb + 1); STEP(2, qb + 2); STEP(3, qb + 3);
            STEP(4, qb + 4); STEP(5, qb + 5); STEP(6, qb + 6); STEP(7, qb + 7);
            STEP(8, qb + 8); STEP(9, qb + 9); STEP(10, qb + 10);
        }
        // d = 28..31: planes 33..36
        STEP(0, 33); STEP(1, 34); STEP(2, 35); STEP(3, 36);
    } else {
        // ---- outputs d = 32..63, planes 27..63 ----
        // preload planes 27..37 at slot plane%11
        LOADP(5, 27); LOADP(6, 28); LOADP(7, 29); LOADP(8, 30); LOADP(9, 31);
        LOADP(10, 32); LOADP(0, 33); LOADP(1, 34); LOADP(2, 35); LOADP(3, 36);
        LOADP(4, 37);
        EMIT_W(4, 10);                                // d = 32 (planes 27..37)
        // d = 33..38: planes 38..43
        STEP(5, 38); STEP(6, 39); STEP(7, 40); STEP(8, 41); STEP(9, 42);
        STEP(10, 43);
        {                                             // d = 39..49: planes 44..54
            const int qb = 44;
            STEP(0, qb + 0); STEP(1, qb + 1); STEP(2, qb + 2); STEP(3, qb + 3);
            STEP(4, qb + 4); STEP(5, qb + 5); STEP(6, qb + 6); STEP(7, qb + 7);
            STEP(8, qb + 8); STEP(9, qb + 9); STEP(10, qb + 10);
        }
        // d = 50..58: planes 55..63
        STEP(0, 55); STEP(1, 56); STEP(2, 57); STEP(3, 58); STEP(4, 59);
        STEP(5, 60); STEP(6, 61); STEP(7, 62); STEP(8, 63);
        // ramp-out d = 59..63 (truncated windows, no loads)
        EMIT_W(9, 9); EMIT_W(10, 8); EMIT_W(11, 7); EMIT_W(12, 6); EMIT_W(13, 5);
    }

    // block reduction
    float a = ssim_sum;
#pragma unroll
    for (int off = 32; off > 0; off >>= 1) a += __shfl_down(a, off, 64);
    __shared__ float red[4];
    int lane = tid & 63, wv = tid >> 6;
    if (lane == 0) red[wv] = a;
    __syncthreads();
    if (tid == 0)
        partials[blockIdx.y * gridDim.x + blockIdx.x] =
            red[0] + red[1] + red[2] + red[3];
}

// ---- Kernel C: final reduction ----
__global__ __launch_bounds__(256) void finalize_kernel(
    const float* __restrict__ partials, int n, float* __restrict__ out) {
    double a = 0.0;
    for (int i = threadIdx.x; i < n; i += 256) a += (double)partials[i];
#pragma unroll
    for (int off = 32; off > 0; off >>= 1) a += __shfl_down(a, off, 64);
    __shared__ double red[4];
    int lane = threadIdx.x & 63, wv = threadIdx.x >> 6;
    if (lane == 0) red[wv] = a;
    __syncthreads();
    if (threadIdx.x == 0) {
        double s = red[0] + red[1] + red[2] + red[3];
        out[0] = (float)(1.0 - s / (double)((long long)NB * VOL));
    }
}

extern "C" void kernel_launch(void* const* d_in, const int* in_sizes, int n_in,
                              void* d_out, int out_size, void* d_ws, size_t ws_size,
                              hipStream_t stream) {
    const float* pred = (const float*)d_in[0];
    const float* targ = (const float*)d_in[1];
    float* out = (float*)d_out;

    // batches per chunk G in {4,2,1}: X (8B/px) + Y (2B/px) + partials
    int G = 4;
    while (G > 1 && (size_t)G * VOL * 10 + 8192 > ws_size) G >>= 1;

    uint2* Xg = (uint2*)d_ws;
    unsigned short* Yg = (unsigned short*)((char*)d_ws + (size_t)G * VOL * 8);
    float* partials = (float*)((char*)d_ws + (size_t)G * VOL * 10);
    const int bpc = G * 144;                   // dblur blocks per (chunk, half)
    const int nchunks = NB / G;

    for (int c = 0; c < nchunks; ++c) {
        hw_blur_kernel<<<dim3(24, D_DIM, G), 256, 0, stream>>>(
            pred, targ, Xg, Yg, c * G);
        dblur_ssim_kernel<<<dim3(bpc, 2), 256, 0, stream>>>(
            (const h4*)Xg, (const _Float16*)Yg, partials + c * 2 * bpc);
    }
    finalize_kernel<<<1, 256, 0, stream>>>(partials, NB * 288, out);
}